// Round 1
// baseline (559.890 us; speedup 1.0000x reference)
//
#include <hip/hip_runtime.h>

// LSTM cell fused kernel, fp32 in/out, bf16x3 split-precision MFMA GEMM.
// ifgo[4096][4096] = [h|x][4096][2048] @ [Wh;Wx][2048][4096] + b_h
// then c' = sig(f)*c + sig(i)*tanh(g); h' = sig(o)*tanh(c').

#define BM 128      // rows per block
#define BNG 32      // gate-cols per block (x4 gates)
#define BK 32       // k per tile
#define KTILES 64   // 2048 / 32

typedef __attribute__((ext_vector_type(8))) short bf16x8;
typedef __attribute__((ext_vector_type(4))) short s16x4;
typedef __attribute__((ext_vector_type(4))) float f32x4;

__device__ __forceinline__ unsigned short f2bf(float f) {
  unsigned int u = __builtin_bit_cast(unsigned int, f);
  u += 0x7fffu + ((u >> 16) & 1u);          // RNE
  return (unsigned short)(u >> 16);
}
__device__ __forceinline__ float bf2f(unsigned short s) {
  return __builtin_bit_cast(float, ((unsigned int)s) << 16);
}
__device__ __forceinline__ float sigm(float v) {
  return 1.0f / (1.0f + __expf(-v));
}
__device__ __forceinline__ float tanh_f(float v) {
  float e = __expf(2.0f * v);
  return 1.0f - 2.0f / (e + 1.0f);
}

__global__ void __launch_bounds__(256, 2) lstm_cell_kernel(
    const float* __restrict__ x, const float* __restrict__ h,
    const float* __restrict__ c, const float* __restrict__ Wh,
    const float* __restrict__ bh, const float* __restrict__ Wx,
    float* __restrict__ out) {
  // LDS: bf16 hi/lo tiles. Rows padded to 40 shorts (80B = 5x16B) -> the
  // bank-quad stride is 5 (odd) so 8 consecutive rows hit 8 distinct
  // 16B bank-quads: b128 reads across 16 lanes are 2-way max (free).
  __shared__ __align__(16) unsigned short Ahi[BM][40];
  __shared__ __align__(16) unsigned short Alo[BM][40];
  __shared__ __align__(16) unsigned short Whi_s[4][BNG][40];
  __shared__ __align__(16) unsigned short Wlo_s[4][BNG][40];

  const int tid  = threadIdx.x;
  const int lane = tid & 63;
  const int wave = tid >> 6;     // 0..3
  const int wm   = wave >> 1;    // 0..1 : 64-row half
  const int wn   = wave & 1;     // 0..1 : 16-col half

  const int bid = blockIdx.x;    // 1024 blocks
  const int mt  = bid & 31;
  const int nt  = bid >> 5;
  const int b0  = mt * BM;       // global row base
  const int j0  = nt * BNG;      // global gate-col base (0..1023 space)

  // A staging map: thread covers rows a_r0 + {0,32,64,96}, 16B chunk a_c
  const int a_c  = tid & 7;
  const int a_r0 = tid >> 3;     // 0..31
  // W staging map: one gate per wave; 16 k-rows x 1 col per thread
  const int w_gt = tid >> 6;          // gate 0..3
  const int w_n  = tid & 31;          // col within tile
  const int w_kh = (tid >> 5) & 1;    // k half (16 rows)
  const int w_col = w_gt * 1024 + j0 + w_n;  // global W column

  const int fc = lane & 15;           // fragment col / A-row lane
  const int k0 = (lane >> 4) * 8;     // fragment k offset

  // accumulators [m-frag][gate], bias-initialized
  f32x4 acc[4][4];
#pragma unroll
  for (int g = 0; g < 4; ++g) {
    float bv = bh[g * 1024 + j0 + wn * 16 + fc];
    f32x4 b4 = {bv, bv, bv, bv};
#pragma unroll
    for (int m = 0; m < 4; ++m) acc[m][g] = b4;
  }

  f32x4 av[4];
  float wv[16];

  auto load_tiles = [&](int kt, f32x4* avp, float* wvp) {
    const float* As = (kt < 32) ? h : x;
    const float* Ws = (kt < 32) ? Wh : Wx;
    const int krow = (kt & 31) * BK;
#pragma unroll
    for (int p = 0; p < 4; ++p) {
      int r = a_r0 + p * 32;
      avp[p] = *reinterpret_cast<const f32x4*>(
          As + (b0 + r) * 1024 + krow + a_c * 4);
    }
#pragma unroll
    for (int e = 0; e < 16; ++e)
      wvp[e] = Ws[(krow + w_kh * 16 + e) * 4096 + w_col];
  };

  load_tiles(0, av, wv);

#pragma unroll 1
  for (int kt = 0; kt < KTILES; ++kt) {
    // ---- convert + write staged regs to LDS ----
#pragma unroll
    for (int p = 0; p < 4; ++p) {
      int r = a_r0 + p * 32;
      s16x4 hi, lo;
#pragma unroll
      for (int j = 0; j < 4; ++j) {
        float f = av[p][j];
        unsigned short hb = f2bf(f);
        hi[j] = (short)hb;
        lo[j] = (short)f2bf(f - bf2f(hb));
      }
      *reinterpret_cast<s16x4*>(&Ahi[r][a_c * 4]) = hi;
      *reinterpret_cast<s16x4*>(&Alo[r][a_c * 4]) = lo;
    }
#pragma unroll
    for (int q0 = 0; q0 < 4; ++q0) {
      int q = (q0 + (w_n >> 3)) & 3;  // stagger k-quad order: kills 4-way
      s16x4 hi, lo;
#pragma unroll
      for (int j = 0; j < 4; ++j) {
        float f = wv[q * 4 + j];
        unsigned short hb = f2bf(f);
        hi[j] = (short)hb;
        lo[j] = (short)f2bf(f - bf2f(hb));
      }
      *reinterpret_cast<s16x4*>(&Whi_s[w_gt][w_n][w_kh * 16 + q * 4]) = hi;
      *reinterpret_cast<s16x4*>(&Wlo_s[w_gt][w_n][w_kh * 16 + q * 4]) = lo;
    }
    __syncthreads();

    // ---- fragments ----
    bf16x8 ah[4], al[4], bhf[4], blf[4];
#pragma unroll
    for (int m = 0; m < 4; ++m) {
      int rr = wm * 64 + m * 16 + fc;
      ah[m] = *reinterpret_cast<const bf16x8*>(&Ahi[rr][k0]);
      al[m] = *reinterpret_cast<const bf16x8*>(&Alo[rr][k0]);
    }
    const int nn = wn * 16 + fc;
#pragma unroll
    for (int g = 0; g < 4; ++g) {
      bhf[g] = *reinterpret_cast<const bf16x8*>(&Whi_s[g][nn][k0]);
      blf[g] = *reinterpret_cast<const bf16x8*>(&Wlo_s[g][nn][k0]);
    }

    // issue next K-tile's global loads under the MFMA cluster
    if (kt + 1 < KTILES) load_tiles(kt + 1, av, wv);

    // ---- bf16x3 MFMA: hi*hi + lo*hi + hi*lo ----
#pragma unroll
    for (int m = 0; m < 4; ++m)
#pragma unroll
      for (int g = 0; g < 4; ++g) {
        acc[m][g] = __builtin_amdgcn_mfma_f32_16x16x32_bf16(
            ah[m], bhf[g], acc[m][g], 0, 0, 0);
        acc[m][g] = __builtin_amdgcn_mfma_f32_16x16x32_bf16(
            al[m], bhf[g], acc[m][g], 0, 0, 0);
        acc[m][g] = __builtin_amdgcn_mfma_f32_16x16x32_bf16(
            ah[m], blf[g], acc[m][g], 0, 0, 0);
      }
    __syncthreads();
  }

  // ---- fused LSTM epilogue ----
  // D layout (16x16x32): col = lane&15, row = (lane>>4)*4 + reg
  const int gcol = j0 + wn * 16 + fc;
  const int fr4 = (lane >> 4) * 4;
#pragma unroll
  for (int m = 0; m < 4; ++m) {
    int grow_base = b0 + wm * 64 + m * 16 + fr4;
#pragma unroll
    for (int r = 0; r < 4; ++r) {
      int grow = grow_base + r;
      float iv = acc[m][0][r];
      float fv = acc[m][1][r];
      float gv = acc[m][2][r];
      float ov = acc[m][3][r];
      float cold = c[grow * 1024 + gcol];
      float cn = sigm(fv) * cold + sigm(iv) * tanh_f(gv);
      float hn = sigm(ov) * tanh_f(cn);
      out[grow * 1024 + gcol] = hn;                   // h_next
      out[4096 * 1024 + grow * 1024 + gcol] = cn;     // c_next
    }
  }
}

extern "C" void kernel_launch(void* const* d_in, const int* in_sizes, int n_in,
                              void* d_out, int out_size, void* d_ws,
                              size_t ws_size, hipStream_t stream) {
  (void)in_sizes; (void)n_in; (void)out_size; (void)d_ws; (void)ws_size;
  const float* x  = (const float*)d_in[0];
  const float* h  = (const float*)d_in[1];
  const float* c  = (const float*)d_in[2];
  const float* Wh = (const float*)d_in[3];
  const float* bh = (const float*)d_in[4];
  const float* Wx = (const float*)d_in[5];
  float* out = (float*)d_out;
  lstm_cell_kernel<<<dim3(1024), dim3(256), 0, stream>>>(x, h, c, Wh, bh, Wx,
                                                         out);
}

// Round 6
// 296.207 us; speedup vs baseline: 1.8902x; 1.8902x over previous
//
#include <hip/hip_runtime.h>

// LSTM cell, fp32 in/out. Split-precision bf16x3 MFMA GEMM:
//   ifgo = [h|x] @ [Wh;Wx] + b_h,  A*W ~= Ahi*Whi + Alo*Whi + Ahi*Wlo
// Round 2 design (resubmit x4; broker never ran it): conversion hoisted to
// two pre-passes writing fragment-packed bf16 hi/lo into d_ws; GEMM hot loop
// is pure global_load_lds + ds_read_b128 + MFMA (no conversion VALU,
// conflict-free lane-linear LDS).

#define BM 128
#define BK 32
#define KTILES 64   // 2048/32

typedef __attribute__((ext_vector_type(8))) short bf16x8;
typedef __attribute__((ext_vector_type(8))) short short8;
typedef __attribute__((ext_vector_type(4))) short s16x4;
typedef __attribute__((ext_vector_type(4))) float f32x4;

__device__ __forceinline__ unsigned short f2bf(float f) {
  unsigned int u = __builtin_bit_cast(unsigned int, f);
  u += 0x7fffu + ((u >> 16) & 1u);  // RNE
  return (unsigned short)(u >> 16);
}
__device__ __forceinline__ float bf2f(unsigned short s) {
  return __builtin_bit_cast(float, ((unsigned int)s) << 16);
}
__device__ __forceinline__ float sigm(float v) { return 1.0f / (1.0f + __expf(-v)); }
__device__ __forceinline__ float tanh_f(float v) {
  float e = __expf(2.0f * v);
  return 1.0f - 2.0f / (e + 1.0f);
}

#define GLOAD_LDS16(gsrc, ldst)                                      \
  __builtin_amdgcn_global_load_lds(                                  \
      (const __attribute__((address_space(1))) void*)(gsrc),         \
      (__attribute__((address_space(3))) void*)(ldst), 16, 0, 0)

// ---------------- conversion passes ----------------
// Packed layout (both A and W): P[kt][grp 0..255][lane 0..63][8 shorts]
//   lane = kq*16 + fc ; A: row = grp*16+fc, k = kt*32+kq*8+e
//                       W: n   = grp*16+fc, k = kt*32+kq*8+e
// => GEMM fragment reads are identity (lane-linear 16B), conflict-free.

__global__ void __launch_bounds__(256) convA_kernel(
    const float* __restrict__ x, const float* __restrict__ h,
    short* __restrict__ PAhi, short* __restrict__ PAlo) {
  int t = blockIdx.x * 256 + threadIdx.x;  // 1M threads
  int lp = t & 63;
  int rg = (t >> 6) & 255;
  int kt = t >> 14;
  int row = rg * 16 + (lp & 15);
  int k = kt * 32 + (lp >> 4) * 8;
  const float* src = (k < 1024) ? (h + row * 1024 + k) : (x + row * 1024 + (k - 1024));
  float v[8];
  *reinterpret_cast<f32x4*>(v) = *reinterpret_cast<const f32x4*>(src);
  *reinterpret_cast<f32x4*>(v + 4) = *reinterpret_cast<const f32x4*>(src + 4);
  short8 hi, lo;
#pragma unroll
  for (int j = 0; j < 8; ++j) {
    unsigned short hb = f2bf(v[j]);
    hi[j] = (short)hb;
    lo[j] = (short)f2bf(v[j] - bf2f(hb));
  }
  *reinterpret_cast<short8*>(PAhi + (size_t)t * 8) = hi;
  *reinterpret_cast<short8*>(PAlo + (size_t)t * 8) = lo;
}

__global__ void __launch_bounds__(256) convW_kernel(
    const float* __restrict__ Wh, const float* __restrict__ Wx,
    short* __restrict__ PWhi, short* __restrict__ PWlo) {
  int t = blockIdx.x * 256 + threadIdx.x;  // 1M threads
  int lp = t & 63;
  int ng = (t >> 6) & 255;
  int kt = t >> 14;
  int n = ng * 16 + (lp & 15);
  int k = kt * 32 + (lp >> 4) * 8;
  const float* src = (k < 1024) ? (Wh + (size_t)k * 4096 + n)
                                : (Wx + (size_t)(k - 1024) * 4096 + n);
  float v[8];
#pragma unroll
  for (int e = 0; e < 8; ++e) v[e] = src[(size_t)e * 4096];
  short8 hi, lo;
#pragma unroll
  for (int j = 0; j < 8; ++j) {
    unsigned short hb = f2bf(v[j]);
    hi[j] = (short)hb;
    lo[j] = (short)f2bf(v[j] - bf2f(hb));
  }
  *reinterpret_cast<short8*>(PWhi + (size_t)t * 8) = hi;
  *reinterpret_cast<short8*>(PWlo + (size_t)t * 8) = lo;
}

// ---------------- GEMM + fused LSTM epilogue ----------------
__global__ void __launch_bounds__(256, 2) lstm_gemm_kernel(
    const short* __restrict__ PAhi, const short* __restrict__ PAlo,
    const short* __restrict__ PWhi, const short* __restrict__ PWlo,
    const float* __restrict__ c, const float* __restrict__ bh,
    float* __restrict__ out) {
  __shared__ __align__(16) char lds[2][32768];  // [buf][mat(4)][rg(8)][1KB]

  const int tid = threadIdx.x;
  const int lane = tid & 63;
  const int wave = tid >> 6;   // 0..3 : stages matrix `wave`
  const int wm = wave >> 1;    // 0..1
  const int wn = wave & 1;     // 0..1

  const int bid = blockIdx.x;  // 1024
  const int mt = bid & 31;
  const int nt = bid >> 5;
  const int b0 = mt * BM;      // row base
  const int j0 = nt * 32;      // gate-col base (0..1023)

  const short* srcbase = (wave == 0) ? PAhi
                       : (wave == 1) ? PAlo
                       : (wave == 2) ? PWhi : PWlo;
  const int ab0 = b0 >> 4;     // A grp base
  const int nt2 = nt * 2;      // W grp: (i>>1)*64 + nt2 + (i&1)

  auto stage = [&](int kt, int buf) {
#pragma unroll
    for (int i = 0; i < 8; ++i) {
      int grp = (wave < 2) ? (ab0 + i) : ((i >> 1) * 64 + nt2 + (i & 1));
      const short* src = srcbase + ((size_t)(kt * 256 + grp) * 512) + lane * 8;
      char* dst = &lds[buf][(wave * 8 + i) * 1024];
      GLOAD_LDS16(src, dst);
    }
  };

  const int fc = lane & 15;
  // accumulators [m][gate], bias-initialized
  f32x4 acc[4][4];
#pragma unroll
  for (int g = 0; g < 4; ++g) {
    float bv = bh[g * 1024 + j0 + wn * 16 + fc];
    f32x4 b4 = {bv, bv, bv, bv};
#pragma unroll
    for (int m = 0; m < 4; ++m) acc[m][g] = b4;
  }

  stage(0, 0);
  __syncthreads();  // drains vmcnt(0): buf0 ready
  int cur = 0;

#pragma unroll 1
  for (int kt = 0; kt < KTILES; ++kt) {
    if (kt + 1 < KTILES) stage(kt + 1, cur ^ 1);  // in-flight under compute

    const char* bp = lds[cur];
    bf16x8 ah[4], al[4], whf[4], wlf[4];
#pragma unroll
    for (int m = 0; m < 4; ++m) {
      ah[m] = *reinterpret_cast<const bf16x8*>(bp + (wm * 4 + m) * 1024 + lane * 16);
      al[m] = *reinterpret_cast<const bf16x8*>(bp + 8192 + (wm * 4 + m) * 1024 + lane * 16);
    }
#pragma unroll
    for (int g = 0; g < 4; ++g) {
      whf[g] = *reinterpret_cast<const bf16x8*>(bp + 16384 + (g * 2 + wn) * 1024 + lane * 16);
      wlf[g] = *reinterpret_cast<const bf16x8*>(bp + 24576 + (g * 2 + wn) * 1024 + lane * 16);
    }

#pragma unroll
    for (int m = 0; m < 4; ++m)
#pragma unroll
      for (int g = 0; g < 4; ++g) {
        acc[m][g] = __builtin_amdgcn_mfma_f32_16x16x32_bf16(ah[m], whf[g], acc[m][g], 0, 0, 0);
        acc[m][g] = __builtin_amdgcn_mfma_f32_16x16x32_bf16(al[m], whf[g], acc[m][g], 0, 0, 0);
        acc[m][g] = __builtin_amdgcn_mfma_f32_16x16x32_bf16(ah[m], wlf[g], acc[m][g], 0, 0, 0);
      }
    __syncthreads();  // buf^1 staged + everyone done reading buf
    cur ^= 1;
  }

  // fused LSTM epilogue; D layout: col=lane&15, row=(lane>>4)*4+reg
  const int gcol = j0 + wn * 16 + fc;
  const int fr4 = (lane >> 4) * 4;
#pragma unroll
  for (int m = 0; m < 4; ++m) {
    int grow_base = b0 + wm * 64 + m * 16 + fr4;
#pragma unroll
    for (int r = 0; r < 4; ++r) {
      int grow = grow_base + r;
      float iv = acc[m][0][r];
      float fv = acc[m][1][r];
      float gv = acc[m][2][r];
      float ov = acc[m][3][r];
      float cold = c[grow * 1024 + gcol];
      float cn = sigm(fv) * cold + sigm(iv) * tanh_f(gv);
      float hn = sigm(ov) * tanh_f(cn);
      out[grow * 1024 + gcol] = hn;
      out[4096 * 1024 + grow * 1024 + gcol] = cn;
    }
  }
}

// ---------------- fallback (round-1 fused kernel, used if ws too small) ----
__global__ void __launch_bounds__(256, 2) lstm_cell_kernel(
    const float* __restrict__ x, const float* __restrict__ h,
    const float* __restrict__ c, const float* __restrict__ Wh,
    const float* __restrict__ bh, const float* __restrict__ Wx,
    float* __restrict__ out) {
  __shared__ __align__(16) unsigned short Ahi[BM][40];
  __shared__ __align__(16) unsigned short Alo[BM][40];
  __shared__ __align__(16) unsigned short Whi_s[4][32][40];
  __shared__ __align__(16) unsigned short Wlo_s[4][32][40];

  const int tid = threadIdx.x;
  const int lane = tid & 63;
  const int wave = tid >> 6;
  const int wm = wave >> 1;
  const int wn = wave & 1;
  const int bid = blockIdx.x;
  const int mt = bid & 31;
  const int nt = bid >> 5;
  const int b0 = mt * BM;
  const int j0 = nt * 32;
  const int a_c = tid & 7;
  const int a_r0 = tid >> 3;
  const int w_gt = tid >> 6;
  const int w_n = tid & 31;
  const int w_kh = (tid >> 5) & 1;
  const int w_col = w_gt * 1024 + j0 + w_n;
  const int fc = lane & 15;
  const int k0 = (lane >> 4) * 8;

  f32x4 acc[4][4];
#pragma unroll
  for (int g = 0; g < 4; ++g) {
    float bv = bh[g * 1024 + j0 + wn * 16 + fc];
    f32x4 b4 = {bv, bv, bv, bv};
#pragma unroll
    for (int m = 0; m < 4; ++m) acc[m][g] = b4;
  }
  f32x4 av[4];
  float wv[16];
  auto load_tiles = [&](int kt, f32x4* avp, float* wvp) {
    const float* As = (kt < 32) ? h : x;
    const float* Ws = (kt < 32) ? Wh : Wx;
    const int krow = (kt & 31) * BK;
#pragma unroll
    for (int p = 0; p < 4; ++p) {
      int r = a_r0 + p * 32;
      avp[p] = *reinterpret_cast<const f32x4*>(As + (b0 + r) * 1024 + krow + a_c * 4);
    }
#pragma unroll
    for (int e = 0; e < 16; ++e) wvp[e] = Ws[(krow + w_kh * 16 + e) * 4096 + w_col];
  };
  load_tiles(0, av, wv);
#pragma unroll 1
  for (int kt = 0; kt < KTILES; ++kt) {
#pragma unroll
    for (int p = 0; p < 4; ++p) {
      int r = a_r0 + p * 32;
      s16x4 hi, lo;
#pragma unroll
      for (int j = 0; j < 4; ++j) {
        float f = av[p][j];
        unsigned short hb = f2bf(f);
        hi[j] = (short)hb;
        lo[j] = (short)f2bf(f - bf2f(hb));
      }
      *reinterpret_cast<s16x4*>(&Ahi[r][a_c * 4]) = hi;
      *reinterpret_cast<s16x4*>(&Alo[r][a_c * 4]) = lo;
    }
#pragma unroll
    for (int q0 = 0; q0 < 4; ++q0) {
      int q = (q0 + (w_n >> 3)) & 3;
      s16x4 hi, lo;
#pragma unroll
      for (int j = 0; j < 4; ++j) {
        float f = wv[q * 4 + j];
        unsigned short hb = f2bf(f);
        hi[j] = (short)hb;
        lo[j] = (short)f2bf(f - bf2f(hb));
      }
      *reinterpret_cast<s16x4*>(&Whi_s[w_gt][w_n][w_kh * 16 + q * 4]) = hi;
      *reinterpret_cast<s16x4*>(&Wlo_s[w_gt][w_n][w_kh * 16 + q * 4]) = lo;
    }
    __syncthreads();
    bf16x8 ah[4], al[4], bhf[4], blf[4];
#pragma unroll
    for (int m = 0; m < 4; ++m) {
      int rr = wm * 64 + m * 16 + fc;
      ah[m] = *reinterpret_cast<const bf16x8*>(&Ahi[rr][k0]);
      al[m] = *reinterpret_cast<const bf16x8*>(&Alo[rr][k0]);
    }
    const int nn = wn * 16 + fc;
#pragma unroll
    for (int g = 0; g < 4; ++g) {
      bhf[g] = *reinterpret_cast<const bf16x8*>(&Whi_s[g][nn][k0]);
      blf[g] = *reinterpret_cast<const bf16x8*>(&Wlo_s[g][nn][k0]);
    }
    if (kt + 1 < KTILES) load_tiles(kt + 1, av, wv);
#pragma unroll
    for (int m = 0; m < 4; ++m)
#pragma unroll
      for (int g = 0; g < 4; ++g) {
        acc[m][g] = __builtin_amdgcn_mfma_f32_16x16x32_bf16(ah[m], bhf[g], acc[m][g], 0, 0, 0);
        acc[m][g] = __builtin_amdgcn_mfma_f32_16x16x32_bf16(al[m], bhf[g], acc[m][g], 0, 0, 0);
        acc[m][g] = __builtin_amdgcn_mfma_f32_16x16x32_bf16(ah[m], blf[g], acc[m][g], 0, 0, 0);
      }
    __syncthreads();
  }
  const int gcol = j0 + wn * 16 + fc;
  const int fr4 = (lane >> 4) * 4;
#pragma unroll
  for (int m = 0; m < 4; ++m) {
    int grow_base = b0 + wm * 64 + m * 16 + fr4;
#pragma unroll
    for (int r = 0; r < 4; ++r) {
      int grow = grow_base + r;
      float iv = acc[m][0][r];
      float fv = acc[m][1][r];
      float gv = acc[m][2][r];
      float ov = acc[m][3][r];
      float cold = c[grow * 1024 + gcol];
      float cn = sigm(fv) * cold + sigm(iv) * tanh_f(gv);
      float hn = sigm(ov) * tanh_f(cn);
      out[grow * 1024 + gcol] = hn;
      out[4096 * 1024 + grow * 1024 + gcol] = cn;
    }
  }
}

extern "C" void kernel_launch(void* const* d_in, const int* in_sizes, int n_in,
                              void* d_out, int out_size, void* d_ws,
                              size_t ws_size, hipStream_t stream) {
  (void)in_sizes; (void)n_in; (void)out_size;
  const float* x = (const float*)d_in[0];
  const float* h = (const float*)d_in[1];
  const float* c = (const float*)d_in[2];
  const float* Wh = (const float*)d_in[3];
  const float* bh = (const float*)d_in[4];
  const float* Wx = (const float*)d_in[5];
  float* out = (float*)d_out;

  const size_t QUAD = (size_t)8 * 1024 * 1024;  // shorts per buffer (16MB)
  if (ws_size >= 4 * QUAD * sizeof(short)) {
    short* PAhi = (short*)d_ws;
    short* PAlo = PAhi + QUAD;
    short* PWhi = PAlo + QUAD;
    short* PWlo = PWhi + QUAD;
    convA_kernel<<<dim3(4096), dim3(256), 0, stream>>>(x, h, PAhi, PAlo);
    convW_kernel<<<dim3(4096), dim3(256), 0, stream>>>(Wh, Wx, PWhi, PWlo);
    lstm_gemm_kernel<<<dim3(1024), dim3(256), 0, stream>>>(PAhi, PAlo, PWhi,
                                                           PWlo, c, bh, out);
  } else {
    lstm_cell_kernel<<<dim3(1024), dim3(256), 0, stream>>>(x, h, c, Wh, bh, Wx,
                                                           out);
  }
}

// Round 7
// 282.800 us; speedup vs baseline: 1.9798x; 1.0474x over previous
//
#include <hip/hip_runtime.h>

// LSTM cell, fp32 in/out. Split-precision bf16x3 MFMA GEMM:
//   ifgo = [h|x] @ [Wh;Wx] + b_h,  A*W ~= Ahi*Whi + Alo*Whi + Ahi*Wlo
// Round 7: conv passes rewritten as LDS-staged transposers with dense
// coalesced global IO (round-6 convs ran ~122us combined due to scattered
// 16B/4B accesses). GEMM kernel byte-identical to round 6 (the control).

#define BM 128
#define BK 32
#define KTILES 64   // 2048/32

typedef __attribute__((ext_vector_type(8))) short bf16x8;
typedef __attribute__((ext_vector_type(8))) short short8;
typedef __attribute__((ext_vector_type(4))) short s16x4;
typedef __attribute__((ext_vector_type(4))) float f32x4;

__device__ __forceinline__ unsigned short f2bf(float f) {
  unsigned int u = __builtin_bit_cast(unsigned int, f);
  u += 0x7fffu + ((u >> 16) & 1u);  // RNE
  return (unsigned short)(u >> 16);
}
__device__ __forceinline__ float bf2f(unsigned short s) {
  return __builtin_bit_cast(float, ((unsigned int)s) << 16);
}
__device__ __forceinline__ float sigm(float v) { return 1.0f / (1.0f + __expf(-v)); }
__device__ __forceinline__ float tanh_f(float v) {
  float e = __expf(2.0f * v);
  return 1.0f - 2.0f / (e + 1.0f);
}

#define GLOAD_LDS16(gsrc, ldst)                                      \
  __builtin_amdgcn_global_load_lds(                                  \
      (const __attribute__((address_space(1))) void*)(gsrc),         \
      (__attribute__((address_space(3))) void*)(ldst), 16, 0, 0)

// ---------------- conversion passes (round-7 rewrite) ----------------
// Packed layout (both A and W): P[kt][grp 0..255][lane 0..63][8 shorts]
//   lane = kq*16 + fc ; A: row = grp*16+fc, k = kt*32+kq*8+e
//                       W: n   = grp*16+fc, k = kt*32+kq*8+e
// => GEMM fragment reads are identity (lane-linear 16B), conflict-free.

// convA: block = [16 rows][256 k] tile. grid = 256 rowgroups x 8 kslabs.
__global__ void __launch_bounds__(256) convA_kernel(
    const float* __restrict__ x, const float* __restrict__ h,
    short* __restrict__ PAhi, short* __restrict__ PAlo) {
  __shared__ __align__(16) float At[16][268];  // 268 pad: bank-spread
  const int bid = blockIdx.x;       // 2048
  const int rg = bid >> 3;          // row-group 0..255
  const int ks = bid & 7;           // k-slab (256 k) 0..7
  const int t = threadIdx.x;

  // read phase: dense f32x4, 16 lanes cover 256B contiguous per row
  {
    const int rr = t >> 4;          // row local 0..15
    const int cc = t & 15;
    const int row = rg * 16 + rr;
    const int kbase = ks * 256;     // uniform h/x split (slab never straddles)
    const float* srcrow = (kbase < 1024) ? (h + (size_t)row * 1024 + kbase)
                                         : (x + (size_t)row * 1024 + (kbase - 1024));
#pragma unroll
    for (int j = 0; j < 4; ++j) {
      *reinterpret_cast<f32x4*>(&At[rr][j * 64 + cc * 4]) =
          *reinterpret_cast<const f32x4*>(srcrow + j * 64 + cc * 4);
    }
  }
  __syncthreads();

  // build phase: thread -> 2 (hi,lo) entry pairs; scalar LDS reads dense
  const int kt_l = t >> 5;          // 0..7
  const int l0 = t & 31;
  const int kt = ks * 8 + kt_l;
  const size_t base = (size_t)(kt * 256 + rg) * 512;  // shorts
#pragma unroll
  for (int half = 0; half < 2; ++half) {
    const int l = l0 + half * 32;
    const int fc = l & 15;
    const int kq = l >> 4;
    short8 hi, lo;
#pragma unroll
    for (int e = 0; e < 8; ++e) {
      float f = At[fc][kt_l * 32 + kq * 8 + e];
      unsigned short hb = f2bf(f);
      hi[e] = (short)hb;
      lo[e] = (short)f2bf(f - bf2f(hb));
    }
    *reinterpret_cast<short8*>(PAhi + base + l * 8) = hi;
    *reinterpret_cast<short8*>(PAlo + base + l * 8) = lo;
  }
}

// convW: block = [32 k][256 n] tile. grid = 64 ktiles x 16 nslabs.
__global__ void __launch_bounds__(256) convW_kernel(
    const float* __restrict__ Wh, const float* __restrict__ Wx,
    short* __restrict__ PWhi, short* __restrict__ PWlo) {
  __shared__ __align__(16) float Wt[32][268];
  const int bid = blockIdx.x;       // 1024
  const int kb = bid >> 4;          // kt 0..63
  const int ns = bid & 15;          // n-slab (256 n) 0..15
  const int t = threadIdx.x;

  // read phase: dense f32x4 along n (W is [k][4096] row-major)
  {
    const int rr = t >> 3;          // k row local 0..31
    const int cc = t & 7;
    const int kg = kb * 32 + rr;    // kb<32 -> Wh, else Wx (uniform per block)
    const float* srcrow = (kb < 32) ? (Wh + (size_t)kg * 4096)
                                    : (Wx + (size_t)(kg - 1024 / 32 * 32 + rr - rr) * 4096 + (size_t)(kg - 1024) * 0);
    // (kept simple & correct below)
    srcrow = (kg < 1024) ? (Wh + (size_t)kg * 4096)
                         : (Wx + (size_t)(kg - 1024) * 4096);
#pragma unroll
    for (int j = 0; j < 8; ++j) {
      const int n = ns * 256 + j * 32 + cc * 4;
      *reinterpret_cast<f32x4*>(&Wt[rr][j * 32 + cc * 4]) =
          *reinterpret_cast<const f32x4*>(srcrow + n);
    }
  }
  __syncthreads();

  // build phase: thread t owns n_local = t; 4 kq entries (transpose via LDS)
  const int fc = t & 15;
  const int grp_l = t >> 4;         // 0..15
  const int nl = t;                 // = grp_l*16 + fc
  const size_t grp = (size_t)ns * 16 + grp_l;
  const size_t base = ((size_t)kb * 256 + grp) * 512;  // shorts
#pragma unroll
  for (int kq = 0; kq < 4; ++kq) {
    short8 hi, lo;
#pragma unroll
    for (int e = 0; e < 8; ++e) {
      float f = Wt[kq * 8 + e][nl];   // dense across lanes -> ~2-way (free)
      unsigned short hb = f2bf(f);
      hi[e] = (short)hb;
      lo[e] = (short)f2bf(f - bf2f(hb));
    }
    *reinterpret_cast<short8*>(PWhi + base + (kq * 16 + fc) * 8) = hi;
    *reinterpret_cast<short8*>(PWlo + base + (kq * 16 + fc) * 8) = lo;
  }
}

// ---------------- GEMM + fused LSTM epilogue (unchanged from round 6) ----
__global__ void __launch_bounds__(256, 2) lstm_gemm_kernel(
    const short* __restrict__ PAhi, const short* __restrict__ PAlo,
    const short* __restrict__ PWhi, const short* __restrict__ PWlo,
    const float* __restrict__ c, const float* __restrict__ bh,
    float* __restrict__ out) {
  __shared__ __align__(16) char lds[2][32768];  // [buf][mat(4)][rg(8)][1KB]

  const int tid = threadIdx.x;
  const int lane = tid & 63;
  const int wave = tid >> 6;   // 0..3 : stages matrix `wave`
  const int wm = wave >> 1;    // 0..1
  const int wn = wave & 1;     // 0..1

  const int bid = blockIdx.x;  // 1024
  const int mt = bid & 31;
  const int nt = bid >> 5;
  const int b0 = mt * BM;      // row base
  const int j0 = nt * 32;      // gate-col base (0..1023)

  const short* srcbase = (wave == 0) ? PAhi
                       : (wave == 1) ? PAlo
                       : (wave == 2) ? PWhi : PWlo;
  const int ab0 = b0 >> 4;     // A grp base
  const int nt2 = nt * 2;      // W grp: (i>>1)*64 + nt2 + (i&1)

  auto stage = [&](int kt, int buf) {
#pragma unroll
    for (int i = 0; i < 8; ++i) {
      int grp = (wave < 2) ? (ab0 + i) : ((i >> 1) * 64 + nt2 + (i & 1));
      const short* src = srcbase + ((size_t)(kt * 256 + grp) * 512) + lane * 8;
      char* dst = &lds[buf][(wave * 8 + i) * 1024];
      GLOAD_LDS16(src, dst);
    }
  };

  const int fc = lane & 15;
  // accumulators [m][gate], bias-initialized
  f32x4 acc[4][4];
#pragma unroll
  for (int g = 0; g < 4; ++g) {
    float bv = bh[g * 1024 + j0 + wn * 16 + fc];
    f32x4 b4 = {bv, bv, bv, bv};
#pragma unroll
    for (int m = 0; m < 4; ++m) acc[m][g] = b4;
  }

  stage(0, 0);
  __syncthreads();  // drains vmcnt(0): buf0 ready
  int cur = 0;

#pragma unroll 1
  for (int kt = 0; kt < KTILES; ++kt) {
    if (kt + 1 < KTILES) stage(kt + 1, cur ^ 1);  // in-flight under compute

    const char* bp = lds[cur];
    bf16x8 ah[4], al[4], whf[4], wlf[4];
#pragma unroll
    for (int m = 0; m < 4; ++m) {
      ah[m] = *reinterpret_cast<const bf16x8*>(bp + (wm * 4 + m) * 1024 + lane * 16);
      al[m] = *reinterpret_cast<const bf16x8*>(bp + 8192 + (wm * 4 + m) * 1024 + lane * 16);
    }
#pragma unroll
    for (int g = 0; g < 4; ++g) {
      whf[g] = *reinterpret_cast<const bf16x8*>(bp + 16384 + (g * 2 + wn) * 1024 + lane * 16);
      wlf[g] = *reinterpret_cast<const bf16x8*>(bp + 24576 + (g * 2 + wn) * 1024 + lane * 16);
    }

#pragma unroll
    for (int m = 0; m < 4; ++m)
#pragma unroll
      for (int g = 0; g < 4; ++g) {
        acc[m][g] = __builtin_amdgcn_mfma_f32_16x16x32_bf16(ah[m], whf[g], acc[m][g], 0, 0, 0);
        acc[m][g] = __builtin_amdgcn_mfma_f32_16x16x32_bf16(al[m], whf[g], acc[m][g], 0, 0, 0);
        acc[m][g] = __builtin_amdgcn_mfma_f32_16x16x32_bf16(ah[m], wlf[g], acc[m][g], 0, 0, 0);
      }
    __syncthreads();  // buf^1 staged + everyone done reading buf
    cur ^= 1;
  }

  // fused LSTM epilogue; D layout: col=lane&15, row=(lane>>4)*4+reg
  const int gcol = j0 + wn * 16 + fc;
  const int fr4 = (lane >> 4) * 4;
#pragma unroll
  for (int m = 0; m < 4; ++m) {
    int grow_base = b0 + wm * 64 + m * 16 + fr4;
#pragma unroll
    for (int r = 0; r < 4; ++r) {
      int grow = grow_base + r;
      float iv = acc[m][0][r];
      float fv = acc[m][1][r];
      float gv = acc[m][2][r];
      float ov = acc[m][3][r];
      float cold = c[grow * 1024 + gcol];
      float cn = sigm(fv) * cold + sigm(iv) * tanh_f(gv);
      float hn = sigm(ov) * tanh_f(cn);
      out[grow * 1024 + gcol] = hn;
      out[4096 * 1024 + grow * 1024 + gcol] = cn;
    }
  }
}

// ---------------- fallback (round-1 fused kernel, used if ws too small) ----
__global__ void __launch_bounds__(256, 2) lstm_cell_kernel(
    const float* __restrict__ x, const float* __restrict__ h,
    const float* __restrict__ c, const float* __restrict__ Wh,
    const float* __restrict__ bh, const float* __restrict__ Wx,
    float* __restrict__ out) {
  __shared__ __align__(16) unsigned short Ahi[BM][40];
  __shared__ __align__(16) unsigned short Alo[BM][40];
  __shared__ __align__(16) unsigned short Whi_s[4][32][40];
  __shared__ __align__(16) unsigned short Wlo_s[4][32][40];

  const int tid = threadIdx.x;
  const int lane = tid & 63;
  const int wave = tid >> 6;
  const int wm = wave >> 1;
  const int wn = wave & 1;
  const int bid = blockIdx.x;
  const int mt = bid & 31;
  const int nt = bid >> 5;
  const int b0 = mt * BM;
  const int j0 = nt * 32;
  const int a_c = tid & 7;
  const int a_r0 = tid >> 3;
  const int w_gt = tid >> 6;
  const int w_n = tid & 31;
  const int w_kh = (tid >> 5) & 1;
  const int w_col = w_gt * 1024 + j0 + w_n;
  const int fc = lane & 15;
  const int k0 = (lane >> 4) * 8;

  f32x4 acc[4][4];
#pragma unroll
  for (int g = 0; g < 4; ++g) {
    float bv = bh[g * 1024 + j0 + wn * 16 + fc];
    f32x4 b4 = {bv, bv, bv, bv};
#pragma unroll
    for (int m = 0; m < 4; ++m) acc[m][g] = b4;
  }
  f32x4 av[4];
  float wv[16];
  auto load_tiles = [&](int kt, f32x4* avp, float* wvp) {
    const float* As = (kt < 32) ? h : x;
    const float* Ws = (kt < 32) ? Wh : Wx;
    const int krow = (kt & 31) * BK;
#pragma unroll
    for (int p = 0; p < 4; ++p) {
      int r = a_r0 + p * 32;
      avp[p] = *reinterpret_cast<const f32x4*>(As + (b0 + r) * 1024 + krow + a_c * 4);
    }
#pragma unroll
    for (int e = 0; e < 16; ++e) wvp[e] = Ws[(krow + w_kh * 16 + e) * 4096 + w_col];
  };
  load_tiles(0, av, wv);
#pragma unroll 1
  for (int kt = 0; kt < KTILES; ++kt) {
#pragma unroll
    for (int p = 0; p < 4; ++p) {
      int r = a_r0 + p * 32;
      s16x4 hi, lo;
#pragma unroll
      for (int j = 0; j < 4; ++j) {
        float f = av[p][j];
        unsigned short hb = f2bf(f);
        hi[j] = (short)hb;
        lo[j] = (short)f2bf(f - bf2f(hb));
      }
      *reinterpret_cast<s16x4*>(&Ahi[r][a_c * 4]) = hi;
      *reinterpret_cast<s16x4*>(&Alo[r][a_c * 4]) = lo;
    }
#pragma unroll
    for (int q0 = 0; q0 < 4; ++q0) {
      int q = (q0 + (w_n >> 3)) & 3;
      s16x4 hi, lo;
#pragma unroll
      for (int j = 0; j < 4; ++j) {
        float f = wv[q * 4 + j];
        unsigned short hb = f2bf(f);
        hi[j] = (short)hb;
        lo[j] = (short)f2bf(f - bf2f(hb));
      }
      *reinterpret_cast<s16x4*>(&Whi_s[w_gt][w_n][w_kh * 16 + q * 4]) = hi;
      *reinterpret_cast<s16x4*>(&Wlo_s[w_gt][w_n][w_kh * 16 + q * 4]) = lo;
    }
    __syncthreads();
    bf16x8 ah[4], al[4], bhf[4], blf[4];
#pragma unroll
    for (int m = 0; m < 4; ++m) {
      int rr = wm * 64 + m * 16 + fc;
      ah[m] = *reinterpret_cast<const bf16x8*>(&Ahi[rr][k0]);
      al[m] = *reinterpret_cast<const bf16x8*>(&Alo[rr][k0]);
    }
    const int nn = wn * 16 + fc;
#pragma unroll
    for (int g = 0; g < 4; ++g) {
      bhf[g] = *reinterpret_cast<const bf16x8*>(&Whi_s[g][nn][k0]);
      blf[g] = *reinterpret_cast<const bf16x8*>(&Wlo_s[g][nn][k0]);
    }
    if (kt + 1 < KTILES) load_tiles(kt + 1, av, wv);
#pragma unroll
    for (int m = 0; m < 4; ++m)
#pragma unroll
      for (int g = 0; g < 4; ++g) {
        acc[m][g] = __builtin_amdgcn_mfma_f32_16x16x32_bf16(ah[m], bhf[g], acc[m][g], 0, 0, 0);
        acc[m][g] = __builtin_amdgcn_mfma_f32_16x16x32_bf16(al[m], bhf[g], acc[m][g], 0, 0, 0);
        acc[m][g] = __builtin_amdgcn_mfma_f32_16x16x32_bf16(ah[m], blf[g], acc[m][g], 0, 0, 0);
      }
    __syncthreads();
  }
  const int gcol = j0 + wn * 16 + fc;
  const int fr4 = (lane >> 4) * 4;
#pragma unroll
  for (int m = 0; m < 4; ++m) {
    int grow_base = b0 + wm * 64 + m * 16 + fr4;
#pragma unroll
    for (int r = 0; r < 4; ++r) {
      int grow = grow_base + r;
      float iv = acc[m][0][r];
      float fv = acc[m][1][r];
      float gv = acc[m][2][r];
      float ov = acc[m][3][r];
      float cold = c[grow * 1024 + gcol];
      float cn = sigm(fv) * cold + sigm(iv) * tanh_f(gv);
      float hn = sigm(ov) * tanh_f(cn);
      out[grow * 1024 + gcol] = hn;
      out[4096 * 1024 + grow * 1024 + gcol] = cn;
    }
  }
}

extern "C" void kernel_launch(void* const* d_in, const int* in_sizes, int n_in,
                              void* d_out, int out_size, void* d_ws,
                              size_t ws_size, hipStream_t stream) {
  (void)in_sizes; (void)n_in; (void)out_size;
  const float* x = (const float*)d_in[0];
  const float* h = (const float*)d_in[1];
  const float* c = (const float*)d_in[2];
  const float* Wh = (const float*)d_in[3];
  const float* bh = (const float*)d_in[4];
  const float* Wx = (const float*)d_in[5];
  float* out = (float*)d_out;

  const size_t QUAD = (size_t)8 * 1024 * 1024;  // shorts per buffer (16MB)
  if (ws_size >= 4 * QUAD * sizeof(short)) {
    short* PAhi = (short*)d_ws;
    short* PAlo = PAhi + QUAD;
    short* PWhi = PAlo + QUAD;
    short* PWlo = PWhi + QUAD;
    convA_kernel<<<dim3(2048), dim3(256), 0, stream>>>(x, h, PAhi, PAlo);
    convW_kernel<<<dim3(1024), dim3(256), 0, stream>>>(Wh, Wx, PWhi, PWlo);
    lstm_gemm_kernel<<<dim3(1024), dim3(256), 0, stream>>>(PAhi, PAlo, PWhi,
                                                           PWlo, c, bh, out);
  } else {
    lstm_cell_kernel<<<dim3(1024), dim3(256), 0, stream>>>(x, h, c, Wh, bh, Wx,
                                                           out);
  }
}